// Round 1
// baseline (793.022 us; speedup 1.0000x reference)
//
#include <hip/hip_runtime.h>
#include <math.h>

#define NIMG 116          // 4*29 images
#define TW 32             // output tile width
#define TH 32             // output tile height
#define PW 42             // patch = tile + 10
#define PH 42

// 11-tap Gaussian (size=11, sigma=1.5), computed per-thread to match fp32 ref
__device__ __forceinline__ void gwin(float w[11]) {
    float s = 0.f;
#pragma unroll
    for (int i = 0; i < 11; i++) {
        float d = (float)(i - 5);
        float v = expf(-(d * d) / 4.5f);   // 2*sigma^2 = 4.5
        w[i] = v; s += v;
    }
    float inv = 1.0f / s;
#pragma unroll
    for (int i = 0; i < 11; i++) w[i] *= inv;
}

__device__ __forceinline__ float sigmoidf(float x) {
    return 1.0f / (1.0f + expf(-x));
}

// One block per 32x32 output tile of one image. Computes separable Gaussian
// filter of {X, Y, XX, YY, XY}, then cs/ssim map sums -> atomicAdd per image.
template <bool SIG>
__global__ __launch_bounds__(256)
void ssim_kernel(const float* __restrict__ X, const float* __restrict__ Y,
                 int N, float* __restrict__ accSsim, float* __restrict__ accCs) {
    __shared__ float sx[PH][PW + 2];   // stride 44 -> conflict-free
    __shared__ float sy[PH][PW + 2];
    __shared__ float h[5][PH][TW];     // horizontally-filtered quantities
    __shared__ float red[8];

    const int tid = threadIdx.x;
    const int img = blockIdx.z;
    const int ox0 = blockIdx.x * TW;
    const int oy0 = blockIdx.y * TH;
    const int M = N - 10;              // VALID output size
    const long base = (long)img * N * N;

    float w[11];
    gwin(w);

    // ---- stage patch (out-of-range -> 0, only used by masked-out outputs) ----
    for (int p = tid; p < PH * PW; p += 256) {
        int py = p / PW, px = p - py * PW;
        int gy = oy0 + py, gx = ox0 + px;
        float xv = 0.f, yv = 0.f;
        if (gy < N && gx < N) {
            xv = X[base + (long)gy * N + gx];
            yv = Y[base + (long)gy * N + gx];
            if (SIG) xv = sigmoidf(xv);
        }
        sx[py][px] = xv;
        sy[py][px] = yv;
    }
    __syncthreads();

    // ---- horizontal pass: 42 rows x 32 cols ----
    for (int p = tid; p < PH * TW; p += 256) {
        int py = p >> 5, px = p & 31;
        float ax = 0, ay = 0, axx = 0, ayy = 0, axy = 0;
#pragma unroll
        for (int t = 0; t < 11; t++) {
            float xv = sx[py][px + t];
            float yv = sy[py][px + t];
            ax  += w[t] * xv;
            ay  += w[t] * yv;
            axx += w[t] * xv * xv;
            ayy += w[t] * yv * yv;
            axy += w[t] * xv * yv;
        }
        h[0][py][px] = ax;
        h[1][py][px] = ay;
        h[2][py][px] = axx;
        h[3][py][px] = ayy;
        h[4][py][px] = axy;
    }
    __syncthreads();

    // ---- vertical pass + SSIM stats ----
    const float C1 = 1e-4f, C2 = 9e-4f;
    float scs = 0.f, sss = 0.f;
    for (int p = tid; p < TH * TW; p += 256) {
        int oy = p >> 5, ox = p & 31;
        int gy = oy0 + oy, gx = ox0 + ox;
        if (gy < M && gx < M) {
            float mu1 = 0, mu2 = 0, exx = 0, eyy = 0, exy = 0;
#pragma unroll
            for (int t = 0; t < 11; t++) {
                mu1 += w[t] * h[0][oy + t][ox];
                mu2 += w[t] * h[1][oy + t][ox];
                exx += w[t] * h[2][oy + t][ox];
                eyy += w[t] * h[3][oy + t][ox];
                exy += w[t] * h[4][oy + t][ox];
            }
            float m11 = mu1 * mu1, m22 = mu2 * mu2, m12 = mu1 * mu2;
            float s1 = exx - m11, s2 = eyy - m22, s12 = exy - m12;
            float cs = (2.f * s12 + C2) / (s1 + s2 + C2);
            float ssim = ((2.f * m12 + C1) / (m11 + m22 + C1)) * cs;
            scs += cs;
            sss += ssim;
        }
    }

    // ---- block reduction (4 waves of 64) ----
    for (int off = 32; off > 0; off >>= 1) {
        scs += __shfl_down(scs, off, 64);
        sss += __shfl_down(sss, off, 64);
    }
    int lane = tid & 63, wv = tid >> 6;
    if (lane == 0) { red[wv] = scs; red[4 + wv] = sss; }
    __syncthreads();
    if (tid == 0) {
        float c = red[0] + red[1] + red[2] + red[3];
        float s = red[4] + red[5] + red[6] + red[7];
        atomicAdd(&accCs[img], c);
        atomicAdd(&accSsim[img], s);
    }
}

// 2x2 average pool (optionally sigmoid on load); one thread per output pixel.
template <bool SIG>
__global__ __launch_bounds__(256)
void pool_kernel(const float* __restrict__ src, float* __restrict__ dst,
                 int N, int total) {
    int idx = blockIdx.x * 256 + threadIdx.x;
    if (idx >= total) return;
    int half = N >> 1;
    int hh = half * half;
    int img = idx / hh;
    int rem = idx - img * hh;
    int i = rem / half;
    int j = rem - i * half;

    const float2* s2 = (const float2*)src;
    long f2base = (long)img * N * half;           // img*N*N in float2 units
    float2 a = s2[f2base + (long)i * N + j];      // row 2i,   cols 2j,2j+1
    float2 b = s2[f2base + (long)i * N + half + j]; // row 2i+1, cols 2j,2j+1

    float ax = a.x, ay = a.y, bx = b.x, by = b.y;
    if (SIG) { ax = sigmoidf(ax); ay = sigmoidf(ay); bx = sigmoidf(bx); by = sigmoidf(by); }
    dst[(long)img * hh + rem] = 0.25f * ((ax + ay) + (bx + by));
}

// acc layout: level l -> [l*2*NIMG .. +NIMG) ssim sums, [+NIMG .. +2*NIMG) cs sums
__global__ __launch_bounds__(128)
void finalize_kernel(const float* __restrict__ acc, float* __restrict__ out) {
    const float wts[5] = {0.0448f, 0.2856f, 0.3001f, 0.2363f, 0.1333f};
    const int Ms[5] = {502, 246, 118, 54, 22};
    int t = threadIdx.x;
    float v = 0.f;
    if (t < NIMG) {
        float prod = 1.f;
#pragma unroll
        for (int l = 0; l < 5; l++) {
            float inv = 1.0f / ((float)Ms[l] * (float)Ms[l]);
            float m = (l < 4) ? acc[l * 2 * NIMG + NIMG + t] * inv   // cs mean
                              : acc[l * 2 * NIMG + t] * inv;          // ssim mean
            m = fmaxf(m, 0.f);                                        // relu
            prod *= powf(m, wts[l]);
        }
        v = prod;
    }
    for (int off = 32; off > 0; off >>= 1) v += __shfl_down(v, off, 64);
    __shared__ float red[2];
    if ((t & 63) == 0) red[t >> 6] = v;
    __syncthreads();
    if (t == 0) out[0] = 1.0f - (red[0] + red[1]) / (float)NIMG;
}

extern "C" void kernel_launch(void* const* d_in, const int* in_sizes, int n_in,
                              void* d_out, int out_size, void* d_ws, size_t ws_size,
                              hipStream_t stream) {
    const float* logits = (const float*)d_in[0];
    const float* targets = (const float*)d_in[1];
    float* out = (float*)d_out;
    float* ws = (float*)d_ws;

    // workspace layout (floats)
    float* acc = ws;                               // 5*2*116 = 1160 floats
    size_t off = 1280;
    float* X1 = ws + off; off += (size_t)NIMG * 256 * 256;
    float* Y1 = ws + off; off += (size_t)NIMG * 256 * 256;
    float* X2 = ws + off; off += (size_t)NIMG * 128 * 128;
    float* Y2 = ws + off; off += (size_t)NIMG * 128 * 128;
    float* X3 = ws + off; off += (size_t)NIMG * 64 * 64;
    float* Y3 = ws + off; off += (size_t)NIMG * 64 * 64;
    float* X4 = ws + off; off += (size_t)NIMG * 32 * 32;
    float* Y4 = ws + off; off += (size_t)NIMG * 32 * 32;

    hipMemsetAsync(acc, 0, 1160 * sizeof(float), stream);

    const float* Xs[5] = {logits, X1, X2, X3, X4};
    const float* Ys[5] = {targets, Y1, Y2, Y3, Y4};
    float* Xd[5] = {nullptr, X1, X2, X3, X4};
    float* Yd[5] = {nullptr, Y1, Y2, Y3, Y4};

    for (int l = 0; l < 5; l++) {
        int N = 512 >> l;
        int M = N - 10;
        int tiles = (M + TW - 1) / TW;
        dim3 grid(tiles, tiles, NIMG);
        if (l == 0)
            ssim_kernel<true><<<grid, 256, 0, stream>>>(Xs[l], Ys[l], N,
                acc + l * 2 * NIMG, acc + l * 2 * NIMG + NIMG);
        else
            ssim_kernel<false><<<grid, 256, 0, stream>>>(Xs[l], Ys[l], N,
                acc + l * 2 * NIMG, acc + l * 2 * NIMG + NIMG);

        if (l < 4) {
            int half = N >> 1;
            int total = NIMG * half * half;
            int blocks = (total + 255) / 256;
            if (l == 0)
                pool_kernel<true><<<blocks, 256, 0, stream>>>(Xs[l], Xd[l + 1], N, total);
            else
                pool_kernel<false><<<blocks, 256, 0, stream>>>(Xs[l], Xd[l + 1], N, total);
            pool_kernel<false><<<blocks, 256, 0, stream>>>(Ys[l], Yd[l + 1], N, total);
        }
    }

    finalize_kernel<<<1, 128, 0, stream>>>(acc, out);
}

// Round 2
// 582.442 us; speedup vs baseline: 1.3615x; 1.3615x over previous
//
#include <hip/hip_runtime.h>
#include <math.h>

#define NIMG 116          // 4*29 images
#define TW 118            // output tile width  (phase-1 columns = TW+10 = 128)
#define TH 16             // output tile height (strips of 8 rows, 2 strips)

// 11-tap Gaussian (size=11, sigma=1.5)
__device__ __forceinline__ void gwin(float w[11]) {
    float s = 0.f;
#pragma unroll
    for (int i = 0; i < 11; i++) {
        float d = (float)(i - 5);
        float v = expf(-(d * d) / 4.5f);   // 2*sigma^2 = 4.5
        w[i] = v; s += v;
    }
    float inv = 1.0f / s;
#pragma unroll
    for (int i = 0; i < 11; i++) w[i] *= inv;
}

__device__ __forceinline__ float sigmoidf(float x) {
    return 1.0f / (1.0f + expf(-x));
}

// One block per 118x16 output tile. Phase 1: vertical Gaussian of
// {X,Y,XX,YY,XY} (thread-per-column, register accumulators, pool fused).
// Phase 2: horizontal Gaussian from LDS via swizzled float4 reads + SSIM map.
template <bool SIG, bool POOL>
__global__ __launch_bounds__(256, 4)
void ssim_kernel(const float* __restrict__ X, const float* __restrict__ Y,
                 int N, int M,
                 float* __restrict__ accSsim, float* __restrict__ accCs,
                 float* __restrict__ poolX, float* __restrict__ poolY) {
    __shared__ float smem[5 * 16 * 128];   // 40960 B exactly -> 4 blocks/CU

    const int tid = threadIdx.x;
    const int img = blockIdx.z;
    const int ox0 = blockIdx.x * TW;
    const int oy0 = blockIdx.y * TH;
    const long base = (long)img * N * N;

    float w[11];
    gwin(w);

    // ================= phase 1: vertical filter (+fused 2x2 pool) ==========
    const int c  = tid & 127;      // tile-local column 0..127
    const int s  = tid >> 7;       // strip 0/1 (rows 8s .. 8s+7 of v)
    const int ci = ox0 + c;        // global column
    const int half = N >> 1;
    const int powned = min(TW, N - ox0);   // pool column ownership (even)

    float a0[8], a1[8], a2[8], a3[8], a4[8];
#pragma unroll
    for (int o = 0; o < 8; o++) { a0[o]=a1[o]=a2[o]=a3[o]=a4[o]=0.f; }

    float px = 0.f, py = 0.f;
#pragma unroll
    for (int i = 0; i < 18; i++) {
        int row = oy0 + 8 * s + i;
        float x = 0.f, y = 0.f;
        if (row < N && ci < N) {
            x = X[base + (long)row * N + ci];
            y = Y[base + (long)row * N + ci];
            if (SIG) x = sigmoidf(x);
        }
        float xx = x * x, yy = y * y, xy = x * y;
#pragma unroll
        for (int o = 0; o < 8; o++) {
            int t = i - o;
            if (t >= 0 && t < 11) {
                float wt = w[t];
                a0[o] += wt * x;  a1[o] += wt * y;
                a2[o] += wt * xx; a3[o] += wt * yy; a4[o] += wt * xy;
            }
        }
        if (POOL && (i & 1) && i < 8) {
            // pool row pair (i-1, i); this strip owns rows 8s..8s+7
            float cx = px + x, cy = py + y;
            float rx = __shfl_down(cx, 1, 64);   // column c+1 (same wave)
            float ry = __shfl_down(cy, 1, 64);
            if (!(c & 1) && c < powned) {
                int orow = (oy0 + 8 * s + i - 1) >> 1;
                int ocol = ci >> 1;
                long pb = (long)img * half * half + (long)orow * half + ocol;
                poolX[pb] = 0.25f * (cx + rx);
                poolY[pb] = 0.25f * (cy + ry);
            }
        }
        px = x; py = y;
    }

    // store v to LDS, column-swizzled by 4*row to spread b128 read banks
#pragma unroll
    for (int o = 0; o < 8; o++) {
        int r = 8 * s + o;
        int cc = (c + 4 * r) & 127;
        smem[0 * 2048 + r * 128 + cc] = a0[o];
        smem[1 * 2048 + r * 128 + cc] = a1[o];
        smem[2 * 2048 + r * 128 + cc] = a2[o];
        smem[3 * 2048 + r * 128 + cc] = a3[o];
        smem[4 * 2048 + r * 128 + cc] = a4[o];
    }
    __syncthreads();

    // ================= phase 2: horizontal filter + SSIM ====================
    const float C1 = 1e-4f, C2 = 9e-4f;
    float scs = 0.f, sss = 0.f;
    {
        const int r = tid >> 4;    // output row within tile
        const int k = tid & 15;    // 8-px column segment
        if (k < 15) {              // segment base 8k must be < 118
            float acc[5][8];
#pragma unroll
            for (int q = 0; q < 5; q++) {
                float rg[20];
#pragma unroll
                for (int j5 = 0; j5 < 5; j5++) {
                    int col = (8 * k + 4 * j5 + 4 * r) & 127;   // swizzled chunk
                    const float4 v4 = *(const float4*)&smem[q * 2048 + r * 128 + col];
                    rg[4 * j5 + 0] = v4.x; rg[4 * j5 + 1] = v4.y;
                    rg[4 * j5 + 2] = v4.z; rg[4 * j5 + 3] = v4.w;
                }
#pragma unroll
                for (int j = 0; j < 8; j++) {
                    float a = 0.f;
#pragma unroll
                    for (int t = 0; t < 11; t++) a += w[t] * rg[j + t];
                    acc[q][j] = a;
                }
            }
            int gy = oy0 + r;
#pragma unroll
            for (int j = 0; j < 8; j++) {
                int lc = 8 * k + j;
                int gx = ox0 + lc;
                if (lc < TW && gx < M && gy < M) {
                    float mu1 = acc[0][j], mu2 = acc[1][j];
                    float exx = acc[2][j], eyy = acc[3][j], exy = acc[4][j];
                    float m11 = mu1 * mu1, m22 = mu2 * mu2, m12 = mu1 * mu2;
                    float s1 = exx - m11, s2 = eyy - m22, s12 = exy - m12;
                    float cs = (2.f * s12 + C2) / (s1 + s2 + C2);
                    float ssim = ((2.f * m12 + C1) / (m11 + m22 + C1)) * cs;
                    scs += cs; sss += ssim;
                }
            }
        }
    }

    // block reduction (reuse smem after barrier)
    for (int off = 32; off > 0; off >>= 1) {
        scs += __shfl_down(scs, off, 64);
        sss += __shfl_down(sss, off, 64);
    }
    __syncthreads();
    int lane = tid & 63, wv = tid >> 6;
    if (lane == 0) { smem[wv] = scs; smem[4 + wv] = sss; }
    __syncthreads();
    if (tid == 0) {
        atomicAdd(&accCs[img],   smem[0] + smem[1] + smem[2] + smem[3]);
        atomicAdd(&accSsim[img], smem[4] + smem[5] + smem[6] + smem[7]);
    }
}

// acc layout: level l -> [l*2*NIMG .. +NIMG) ssim sums, [+NIMG .. +2*NIMG) cs sums
__global__ __launch_bounds__(128)
void finalize_kernel(const float* __restrict__ acc, float* __restrict__ out) {
    const float wts[5] = {0.0448f, 0.2856f, 0.3001f, 0.2363f, 0.1333f};
    const int Ms[5] = {502, 246, 118, 54, 22};
    int t = threadIdx.x;
    float v = 0.f;
    if (t < NIMG) {
        float prod = 1.f;
#pragma unroll
        for (int l = 0; l < 5; l++) {
            float inv = 1.0f / ((float)Ms[l] * (float)Ms[l]);
            float m = (l < 4) ? acc[l * 2 * NIMG + NIMG + t] * inv   // cs mean
                              : acc[l * 2 * NIMG + t] * inv;          // ssim mean
            m = fmaxf(m, 0.f);                                        // relu
            prod *= powf(m, wts[l]);
        }
        v = prod;
    }
    for (int off = 32; off > 0; off >>= 1) v += __shfl_down(v, off, 64);
    __shared__ float red[2];
    if ((t & 63) == 0) red[t >> 6] = v;
    __syncthreads();
    if (t == 0) out[0] = 1.0f - (red[0] + red[1]) / (float)NIMG;
}

extern "C" void kernel_launch(void* const* d_in, const int* in_sizes, int n_in,
                              void* d_out, int out_size, void* d_ws, size_t ws_size,
                              hipStream_t stream) {
    const float* logits = (const float*)d_in[0];
    const float* targets = (const float*)d_in[1];
    float* out = (float*)d_out;
    float* ws = (float*)d_ws;

    // workspace layout (floats)
    float* acc = ws;                               // 5*2*116 = 1160 floats
    size_t off = 1280;
    float* X1 = ws + off; off += (size_t)NIMG * 256 * 256;
    float* Y1 = ws + off; off += (size_t)NIMG * 256 * 256;
    float* X2 = ws + off; off += (size_t)NIMG * 128 * 128;
    float* Y2 = ws + off; off += (size_t)NIMG * 128 * 128;
    float* X3 = ws + off; off += (size_t)NIMG * 64 * 64;
    float* Y3 = ws + off; off += (size_t)NIMG * 64 * 64;
    float* X4 = ws + off; off += (size_t)NIMG * 32 * 32;
    float* Y4 = ws + off; off += (size_t)NIMG * 32 * 32;

    hipMemsetAsync(acc, 0, 1160 * sizeof(float), stream);

    const float* Xs[5] = {logits, X1, X2, X3, X4};
    const float* Ys[5] = {targets, Y1, Y2, Y3, Y4};
    float* Xd[5] = {X1, X2, X3, X4, nullptr};
    float* Yd[5] = {Y1, Y2, Y3, Y4, nullptr};
    const int Ms[5] = {502, 246, 118, 54, 22};

    for (int l = 0; l < 5; l++) {
        int N = 512 >> l;
        int M = Ms[l];
        dim3 grid((N + TW - 1) / TW, N / TH, NIMG);   // covers pool cols/rows too
        float* aS = acc + l * 2 * NIMG;
        float* aC = acc + l * 2 * NIMG + NIMG;
        if (l == 0)
            ssim_kernel<true, true><<<grid, 256, 0, stream>>>(
                Xs[l], Ys[l], N, M, aS, aC, Xd[l], Yd[l]);
        else if (l < 4)
            ssim_kernel<false, true><<<grid, 256, 0, stream>>>(
                Xs[l], Ys[l], N, M, aS, aC, Xd[l], Yd[l]);
        else
            ssim_kernel<false, false><<<grid, 256, 0, stream>>>(
                Xs[l], Ys[l], N, M, aS, aC, nullptr, nullptr);
    }

    finalize_kernel<<<1, 128, 0, stream>>>(acc, out);
}

// Round 3
// 508.055 us; speedup vs baseline: 1.5609x; 1.1464x over previous
//
#include <hip/hip_runtime.h>
#include <math.h>

#define NIMG 116          // 4*29 images
#define TW 118            // output tile width  (phase-1 columns = TW+10 = 128)
#define TH 16             // output tile height (strips of 8 rows, 2 strips)

// 11-tap Gaussian (size=11, sigma=1.5), fp32 values precomputed to match
// the reference's fp32 computation (error ~1e-7, threshold 1.9e-2).
static constexpr float W[11] = {
    0.00102838f, 0.00759876f, 0.03600078f, 0.10936075f, 0.21300554f,
    0.26601172f, 0.21300554f, 0.10936075f, 0.03600078f, 0.00759876f,
    0.00102838f};

__device__ __forceinline__ float frcp(float x) {
    return __builtin_amdgcn_rcpf(x);
}

__device__ __forceinline__ float fsig(float x) {
    // sigmoid(x) = 1/(1+exp(-x)); v_exp_f32 + v_rcp_f32, ~1 ulp each
    float e = __builtin_amdgcn_exp2f(x * -1.4426950408889634f);
    return frcp(1.0f + e);
}

// One block per 118x16 output tile. Phase 1: vertical Gaussian of
// {X,Y,XX,YY,XY} (thread-per-column, register accumulators, pool fused).
// Phase 2: horizontal Gaussian from LDS via swizzled float4 reads + SSIM map.
template <bool SIG, bool POOL>
__global__ __launch_bounds__(256, 4)
void ssim_kernel(const float* __restrict__ X, const float* __restrict__ Y,
                 int N, int M,
                 float* __restrict__ accSsim, float* __restrict__ accCs,
                 float* __restrict__ poolX, float* __restrict__ poolY) {
    __shared__ float smem[5 * 16 * 128];   // 40960 B exactly -> 4 blocks/CU

    const int tid = threadIdx.x;
    const int img = blockIdx.z;
    const int ox0 = blockIdx.x * TW;
    const int oy0 = blockIdx.y * TH;
    const long base = (long)img * N * N;

    // ================= phase 1: vertical filter (+fused 2x2 pool) ==========
    const int c  = tid & 127;      // tile-local column 0..127
    const int s  = tid >> 7;       // strip 0/1 (rows 8s .. 8s+7 of v)
    const int ci = ox0 + c;        // global column
    const int cic = min(ci, N - 1);          // clamped (no predication)
    const int half = N >> 1;
    const int powned = min(TW, N - ox0);     // pool column ownership (even)

    const float* __restrict__ Xb = X + base;
    const float* __restrict__ Yb = Y + base;

    float a0[8], a1[8], a2[8], a3[8], a4[8];
#pragma unroll
    for (int o = 0; o < 8; o++) { a0[o]=a1[o]=a2[o]=a3[o]=a4[o]=0.f; }

    float px = 0.f, py = 0.f;
#pragma unroll
    for (int i = 0; i < 18; i++) {
        int row = oy0 + 8 * s + i;
        int rc = min(row, N - 1);            // clamped (no predication)
        float x = Xb[(long)rc * N + cic];
        float y = Yb[(long)rc * N + cic];
        if (SIG) x = fsig(x);
        float xx = x * x, yy = y * y, xy = x * y;
#pragma unroll
        for (int o = 0; o < 8; o++) {
            int t = i - o;
            if (t >= 0 && t < 11) {          // folds statically after unroll
                a0[o] = fmaf(W[t], x,  a0[o]);
                a1[o] = fmaf(W[t], y,  a1[o]);
                a2[o] = fmaf(W[t], xx, a2[o]);
                a3[o] = fmaf(W[t], yy, a3[o]);
                a4[o] = fmaf(W[t], xy, a4[o]);
            }
        }
        if (POOL && (i & 1) && i < 8) {
            // pool row pair (i-1, i); this strip owns rows 8s..8s+7
            float cx = px + x, cy = py + y;
            float rx = __shfl_down(cx, 1, 64);   // column c+1 (same wave)
            float ry = __shfl_down(cy, 1, 64);
            if (!(c & 1) && c < powned) {
                int orow = (oy0 + 8 * s + i - 1) >> 1;
                int ocol = ci >> 1;
                long pb = (long)img * half * half + (long)orow * half + ocol;
                poolX[pb] = 0.25f * (cx + rx);
                poolY[pb] = 0.25f * (cy + ry);
            }
        }
        px = x; py = y;
    }

    // store v to LDS, column-swizzled by 4*row to spread b128 read banks
#pragma unroll
    for (int o = 0; o < 8; o++) {
        int r = 8 * s + o;
        int cc = (c + 4 * r) & 127;
        smem[0 * 2048 + r * 128 + cc] = a0[o];
        smem[1 * 2048 + r * 128 + cc] = a1[o];
        smem[2 * 2048 + r * 128 + cc] = a2[o];
        smem[3 * 2048 + r * 128 + cc] = a3[o];
        smem[4 * 2048 + r * 128 + cc] = a4[o];
    }
    __syncthreads();

    // ================= phase 2: horizontal filter + SSIM ====================
    const float C1 = 1e-4f, C2 = 9e-4f;
    float scs = 0.f, sss = 0.f;
    {
        const int r = tid >> 4;    // output row within tile
        const int k = tid & 15;    // 8-px column segment
        if (k < 15) {              // segment base 8k must be < 118
            float acc[5][8];
#pragma unroll
            for (int q = 0; q < 5; q++) {
                float rg[20];
#pragma unroll
                for (int j5 = 0; j5 < 5; j5++) {
                    int col = (8 * k + 4 * j5 + 4 * r) & 127;   // swizzled chunk
                    const float4 v4 = *(const float4*)&smem[q * 2048 + r * 128 + col];
                    rg[4 * j5 + 0] = v4.x; rg[4 * j5 + 1] = v4.y;
                    rg[4 * j5 + 2] = v4.z; rg[4 * j5 + 3] = v4.w;
                }
#pragma unroll
                for (int j = 0; j < 8; j++) {
                    float a = 0.f;
#pragma unroll
                    for (int t = 0; t < 11; t++) a = fmaf(W[t], rg[j + t], a);
                    acc[q][j] = a;
                }
            }
            int gy = oy0 + r;
#pragma unroll
            for (int j = 0; j < 8; j++) {
                int lc = 8 * k + j;
                int gx = ox0 + lc;
                if (lc < TW && gx < M && gy < M) {
                    float mu1 = acc[0][j], mu2 = acc[1][j];
                    float exx = acc[2][j], eyy = acc[3][j], exy = acc[4][j];
                    float m11 = mu1 * mu1, m22 = mu2 * mu2, m12 = mu1 * mu2;
                    float s1 = exx - m11, s2 = eyy - m22, s12 = exy - m12;
                    float cs = (2.f * s12 + C2) * frcp(s1 + s2 + C2);
                    float ssim = (2.f * m12 + C1) * frcp(m11 + m22 + C1) * cs;
                    scs += cs; sss += ssim;
                }
            }
        }
    }

    // block reduction (reuse smem after barrier)
    for (int off = 32; off > 0; off >>= 1) {
        scs += __shfl_down(scs, off, 64);
        sss += __shfl_down(sss, off, 64);
    }
    __syncthreads();
    int lane = tid & 63, wv = tid >> 6;
    if (lane == 0) { smem[wv] = scs; smem[4 + wv] = sss; }
    __syncthreads();
    if (tid == 0) {
        atomicAdd(&accCs[img],   smem[0] + smem[1] + smem[2] + smem[3]);
        atomicAdd(&accSsim[img], smem[4] + smem[5] + smem[6] + smem[7]);
    }
}

// acc layout: level l -> [l*2*NIMG .. +NIMG) ssim sums, [+NIMG .. +2*NIMG) cs sums
__global__ __launch_bounds__(128)
void finalize_kernel(const float* __restrict__ acc, float* __restrict__ out) {
    const float wts[5] = {0.0448f, 0.2856f, 0.3001f, 0.2363f, 0.1333f};
    const int Ms[5] = {502, 246, 118, 54, 22};
    int t = threadIdx.x;
    float v = 0.f;
    if (t < NIMG) {
        float prod = 1.f;
#pragma unroll
        for (int l = 0; l < 5; l++) {
            float inv = 1.0f / ((float)Ms[l] * (float)Ms[l]);
            float m = (l < 4) ? acc[l * 2 * NIMG + NIMG + t] * inv   // cs mean
                              : acc[l * 2 * NIMG + t] * inv;          // ssim mean
            m = fmaxf(m, 0.f);                                        // relu
            prod *= powf(m, wts[l]);
        }
        v = prod;
    }
    for (int off = 32; off > 0; off >>= 1) v += __shfl_down(v, off, 64);
    __shared__ float red[2];
    if ((t & 63) == 0) red[t >> 6] = v;
    __syncthreads();
    if (t == 0) out[0] = 1.0f - (red[0] + red[1]) / (float)NIMG;
}

extern "C" void kernel_launch(void* const* d_in, const int* in_sizes, int n_in,
                              void* d_out, int out_size, void* d_ws, size_t ws_size,
                              hipStream_t stream) {
    const float* logits = (const float*)d_in[0];
    const float* targets = (const float*)d_in[1];
    float* out = (float*)d_out;
    float* ws = (float*)d_ws;

    // workspace layout (floats)
    float* acc = ws;                               // 5*2*116 = 1160 floats
    size_t off = 1280;
    float* X1 = ws + off; off += (size_t)NIMG * 256 * 256;
    float* Y1 = ws + off; off += (size_t)NIMG * 256 * 256;
    float* X2 = ws + off; off += (size_t)NIMG * 128 * 128;
    float* Y2 = ws + off; off += (size_t)NIMG * 128 * 128;
    float* X3 = ws + off; off += (size_t)NIMG * 64 * 64;
    float* Y3 = ws + off; off += (size_t)NIMG * 64 * 64;
    float* X4 = ws + off; off += (size_t)NIMG * 32 * 32;
    float* Y4 = ws + off; off += (size_t)NIMG * 32 * 32;

    hipMemsetAsync(acc, 0, 1160 * sizeof(float), stream);

    const float* Xs[5] = {logits, X1, X2, X3, X4};
    const float* Ys[5] = {targets, Y1, Y2, Y3, Y4};
    float* Xd[5] = {X1, X2, X3, X4, nullptr};
    float* Yd[5] = {Y1, Y2, Y3, Y4, nullptr};
    const int Ms[5] = {502, 246, 118, 54, 22};

    for (int l = 0; l < 5; l++) {
        int N = 512 >> l;
        int M = Ms[l];
        dim3 grid((N + TW - 1) / TW, N / TH, NIMG);   // covers pool cols/rows too
        float* aS = acc + l * 2 * NIMG;
        float* aC = acc + l * 2 * NIMG + NIMG;
        if (l == 0)
            ssim_kernel<true, true><<<grid, 256, 0, stream>>>(
                Xs[l], Ys[l], N, M, aS, aC, Xd[l], Yd[l]);
        else if (l < 4)
            ssim_kernel<false, true><<<grid, 256, 0, stream>>>(
                Xs[l], Ys[l], N, M, aS, aC, Xd[l], Yd[l]);
        else
            ssim_kernel<false, false><<<grid, 256, 0, stream>>>(
                Xs[l], Ys[l], N, M, aS, aC, nullptr, nullptr);
    }

    finalize_kernel<<<1, 128, 0, stream>>>(acc, out);
}